// Round 2
// baseline (514.330 us; speedup 1.0000x reference)
//
#include <hip/hip_runtime.h>
#include <math.h>

#define TT 128
#define BB 4
#define NT (BB*TT*TT)                 // 65536 elements per [B,T,T]
#define N4 ((size_t)BB*TT*TT*TT)      // 8388608 elements per [B,T,T,T]
#define TEN3(b,x,y) (((b)*TT + (x))*TT + (y))

typedef _Float16 h8 __attribute__((ext_vector_type(8)));
typedef float    f8 __attribute__((ext_vector_type(8)));

__device__ __forceinline__ float sigm(float x) { return 1.0f / (1.0f + __expf(-x)); }
__device__ __forceinline__ float4 ld4(const float* __restrict__ p) {
    return *reinterpret_cast<const float4*>(p);
}
__device__ __forceinline__ f8 ldf8(const float* __restrict__ p) {
    return *reinterpret_cast<const f8*>(p);
}
__device__ __forceinline__ f8 cvt8(const h8 h) {
    f8 r;
    #pragma unroll
    for (int e = 0; e < 8; ++e) r[e] = (float)h[e];
    return r;
}
__device__ __forceinline__ float4 mul4(const float4 a, const float4 b) {
    return make_float4(a.x*b.x, a.y*b.y, a.z*b.z, a.w*b.w);
}
__device__ __forceinline__ float4 fma4s(const float s, const float4 v, const float4 acc) {
    return make_float4(fmaf(s, v.x, acc.x), fmaf(s, v.y, acc.y),
                       fmaf(s, v.z, acc.z), fmaf(s, v.w, acc.w));
}
__device__ __forceinline__ float4 fma4v(const float4 s, const float4 v, const float4 acc) {
    return make_float4(fmaf(s.x, v.x, acc.x), fmaf(s.y, v.y, acc.y),
                       fmaf(s.z, v.z, acc.z), fmaf(s.w, v.w, acc.w));
}
__device__ __forceinline__ float dot4(const float4 a, const float4 b) {
    return a.x*b.x + a.y*b.y + a.z*b.z + a.w*b.w;
}

// ---------------- shared: per-iteration prep ----------------
__global__ __launch_bounds__(256) void prep_kernel(
    const float* __restrict__ q_s, const float* __restrict__ q_h, const float* __restrict__ q_t,
    const float* __restrict__ span, const float* __restrict__ ph, const float* __restrict__ pt,
    float* __restrict__ sig_s, float* __restrict__ sig_h, float* __restrict__ sig_t,
    float* __restrict__ acc_s, float* __restrict__ acc_h, float* __restrict__ acc_t)
{
    const int idx = blockIdx.x * 256 + threadIdx.x;
    sig_s[idx] = sigm(q_s[idx]);
    sig_h[idx] = sigm(q_h[idx]);
    sig_t[idx] = sigm(q_t[idx]);
    acc_s[idx] = span[idx];
    acc_h[idx] = ph[idx];
    acc_t[idx] = pt[idx];
}

// ---------------- fast path: fp16 pre-masked tensors ----------------
__device__ __forceinline__ void mask_cvt_store(
    const float* __restrict__ v, size_t idx,
    const float4 m0, const float4 m1, _Float16* __restrict__ o)
{
    const float4 a = ld4(v + idx);
    const float4 b = ld4(v + idx + 4);
    h8 h;
    h[0]=(_Float16)(a.x*m0.x); h[1]=(_Float16)(a.y*m0.y);
    h[2]=(_Float16)(a.z*m0.z); h[3]=(_Float16)(a.w*m0.w);
    h[4]=(_Float16)(b.x*m1.x); h[5]=(_Float16)(b.y*m1.y);
    h[6]=(_Float16)(b.z*m1.z); h[7]=(_Float16)(b.w*m1.w);
    *reinterpret_cast<h8*>(o + idx) = h;
}

__global__ __launch_bounds__(256) void pm_kernel(
    const float* __restrict__ rspan_psh, const float* __restrict__ rspan_pst, const float* __restrict__ m_r,
    const float* __restrict__ fspan_psh, const float* __restrict__ fspan_pst, const float* __restrict__ m_f,
    const float* __restrict__ ph_sib,    const float* __restrict__ pt_sib,    const float* __restrict__ m_sb,
    const float* __restrict__ ph_cop,    const float* __restrict__ pt_cop,    const float* __restrict__ m_cp,
    _Float16* __restrict__ t_r1, _Float16* __restrict__ t_r2,
    _Float16* __restrict__ t_f3, _Float16* __restrict__ t_f4,
    _Float16* __restrict__ t_s6, _Float16* __restrict__ t_s9,
    _Float16* __restrict__ t_c7, _Float16* __restrict__ t_c11)
{
    const size_t idx = ((size_t)blockIdx.x * 256 + threadIdx.x) * 8;
    {
        const float4 m0 = ld4(m_r + idx), m1 = ld4(m_r + idx + 4);
        mask_cvt_store(rspan_psh, idx, m0, m1, t_r1);
        mask_cvt_store(rspan_pst, idx, m0, m1, t_r2);
    }
    {
        const float4 m0 = ld4(m_f + idx), m1 = ld4(m_f + idx + 4);
        mask_cvt_store(fspan_psh, idx, m0, m1, t_f3);
        mask_cvt_store(fspan_pst, idx, m0, m1, t_f4);
    }
    {
        const float4 m0 = ld4(m_sb + idx), m1 = ld4(m_sb + idx + 4);
        mask_cvt_store(ph_sib, idx, m0, m1, t_s6);
        mask_cvt_store(pt_sib, idx, m0, m1, t_s9);
    }
    {
        const float4 m0 = ld4(m_cp + idx), m1 = ld4(m_cp + idx + 4);
        mask_cvt_store(ph_cop, idx, m0, m1, t_c7);
        mask_cvt_store(pt_cop, idx, m0, m1, t_c11);
    }
}

// K1h: block fixed (b,j), 16 i-rows per block (2 steps x 8 sub-rows).
// (1) span[j,k] += sh[i,j]*r1   (2) span[j,k] += st[i,k]*r2
// (5) ph[i,j]  += sum_k ss[j,k]*r1
// (4) span[i,j] += sum_k st[j,k]*f4   (12) pt[j,k] += ss[i,j]*f4
__global__ __launch_bounds__(128) void k1h_kernel(
    const _Float16* __restrict__ t_r1, const _Float16* __restrict__ t_r2,
    const _Float16* __restrict__ t_f4,
    const float* __restrict__ sig_s, const float* __restrict__ sig_h, const float* __restrict__ sig_t,
    float* __restrict__ acc_s, float* __restrict__ acc_h, float* __restrict__ acc_t)
{
    const int j = blockIdx.y, b = blockIdx.z;
    const int i0 = blockIdx.x * 16;
    const int sub = threadIdx.x >> 4;   // 0..7
    const int kq  = threadIdx.x & 15;
    const int k8  = kq << 3;

    const f8 ss_jk = ldf8(&sig_s[TEN3(b, j, k8)]);
    const f8 st_jk = ldf8(&sig_t[TEN3(b, j, k8)]);

    f8 accspan = {0,0,0,0,0,0,0,0};
    f8 accpt   = {0,0,0,0,0,0,0,0};

    const size_t base = (size_t)b * TT * TT * TT + (size_t)j * TT + k8;

    #pragma unroll
    for (int step = 0; step < 2; ++step) {
        const int i = i0 + step * 8 + sub;
        const size_t rb = base + (size_t)i * (TT * TT);

        const f8 v1 = cvt8(*reinterpret_cast<const h8*>(t_r1 + rb));
        const f8 v2 = cvt8(*reinterpret_cast<const h8*>(t_r2 + rb));
        const f8 v4 = cvt8(*reinterpret_cast<const h8*>(t_f4 + rb));

        const float sh_ij = sig_h[TEN3(b, i, j)];
        const float ss_ij = sig_s[TEN3(b, i, j)];
        const f8 st_ik = ldf8(&sig_t[TEN3(b, i, k8)]);

        float red5 = 0.f, red4 = 0.f;
        #pragma unroll
        for (int e = 0; e < 8; ++e) {
            accspan[e] = fmaf(sh_ij, v1[e], accspan[e]);       // (1)
            accspan[e] = fmaf(st_ik[e], v2[e], accspan[e]);    // (2)
            accpt[e]   = fmaf(ss_ij, v4[e], accpt[e]);         // (12)
            red5 += ss_jk[e] * v1[e];                          // (5)
            red4 += st_jk[e] * v4[e];                          // (4)
        }
        #pragma unroll
        for (int off = 8; off; off >>= 1) {
            red5 += __shfl_xor(red5, off, 64);
            red4 += __shfl_xor(red4, off, 64);
        }
        if (kq == 0) {
            atomicAdd(&acc_h[TEN3(b, i, j)], red5);
            atomicAdd(&acc_s[TEN3(b, i, j)], red4);
        }
    }

    #pragma unroll
    for (int e = 0; e < 8; ++e) {
        accspan[e] += __shfl_xor(accspan[e], 16, 64);
        accspan[e] += __shfl_xor(accspan[e], 32, 64);
        accpt[e]   += __shfl_xor(accpt[e],   16, 64);
        accpt[e]   += __shfl_xor(accpt[e],   32, 64);
    }
    if ((threadIdx.x & 63) < 16) {
        const int o = TEN3(b, j, k8);
        #pragma unroll
        for (int e = 0; e < 8; ++e) {
            atomicAdd(&acc_s[o + e], accspan[e]);
            atomicAdd(&acc_t[o + e], accpt[e]);
        }
    }
}

// K2h: block fixed (b,i), 16 j-rows per block; fully contiguous reads.
// (3) span[i,j] += sum_k sh[i,k]*f3    (8)  ph[i,k] += ss[i,j]*f3
// (6) ph[i,j]  += sum_k sh[i,k]*s6     (9)  pt[i,j] += sum_k st[i,k]*s9
// (7) ph[i,k]  += sh[j,k]*c7           (11) pt[i,k] += st[j,k]*c11
// (10) pt[i,k] += ss[j,k]*r2
__global__ __launch_bounds__(128) void k2h_kernel(
    const _Float16* __restrict__ t_f3, const _Float16* __restrict__ t_s6,
    const _Float16* __restrict__ t_s9, const _Float16* __restrict__ t_c7,
    const _Float16* __restrict__ t_c11, const _Float16* __restrict__ t_r2,
    const float* __restrict__ sig_s, const float* __restrict__ sig_h, const float* __restrict__ sig_t,
    float* __restrict__ acc_s, float* __restrict__ acc_h, float* __restrict__ acc_t)
{
    const int i = blockIdx.y, b = blockIdx.z;
    const int j0 = blockIdx.x * 16;
    const int sub = threadIdx.x >> 4;
    const int kq  = threadIdx.x & 15;
    const int k8  = kq << 3;

    const f8 sh_ik = ldf8(&sig_h[TEN3(b, i, k8)]);
    const f8 st_ik = ldf8(&sig_t[TEN3(b, i, k8)]);

    f8 accph = {0,0,0,0,0,0,0,0};
    f8 accpt = {0,0,0,0,0,0,0,0};

    const size_t base = (size_t)b * TT * TT * TT + (size_t)i * (TT * TT) + k8;

    #pragma unroll
    for (int step = 0; step < 2; ++step) {
        const int j = j0 + step * 8 + sub;
        const size_t rb = base + (size_t)j * TT;

        const f8 v3  = cvt8(*reinterpret_cast<const h8*>(t_f3  + rb));
        const f8 v6  = cvt8(*reinterpret_cast<const h8*>(t_s6  + rb));
        const f8 v9  = cvt8(*reinterpret_cast<const h8*>(t_s9  + rb));
        const f8 v7  = cvt8(*reinterpret_cast<const h8*>(t_c7  + rb));
        const f8 v11 = cvt8(*reinterpret_cast<const h8*>(t_c11 + rb));
        const f8 v10 = cvt8(*reinterpret_cast<const h8*>(t_r2  + rb));

        const float ss_ij = sig_s[TEN3(b, i, j)];
        const f8 sh_jk = ldf8(&sig_h[TEN3(b, j, k8)]);
        const f8 st_jk = ldf8(&sig_t[TEN3(b, j, k8)]);
        const f8 ss_jk = ldf8(&sig_s[TEN3(b, j, k8)]);

        float red3 = 0.f, red6 = 0.f, red9 = 0.f;
        #pragma unroll
        for (int e = 0; e < 8; ++e) {
            accph[e] = fmaf(ss_ij,    v3[e],  accph[e]);   // (8)
            accph[e] = fmaf(sh_jk[e], v7[e],  accph[e]);   // (7)
            accpt[e] = fmaf(st_jk[e], v11[e], accpt[e]);   // (11)
            accpt[e] = fmaf(ss_jk[e], v10[e], accpt[e]);   // (10)
            red3 += sh_ik[e] * v3[e];                      // (3)
            red6 += sh_ik[e] * v6[e];                      // (6)
            red9 += st_ik[e] * v9[e];                      // (9)
        }
        #pragma unroll
        for (int off = 8; off; off >>= 1) {
            red3 += __shfl_xor(red3, off, 64);
            red6 += __shfl_xor(red6, off, 64);
            red9 += __shfl_xor(red9, off, 64);
        }
        if (kq == 0) {
            atomicAdd(&acc_s[TEN3(b, i, j)], red3);
            atomicAdd(&acc_h[TEN3(b, i, j)], red6);
            atomicAdd(&acc_t[TEN3(b, i, j)], red9);
        }
    }

    #pragma unroll
    for (int e = 0; e < 8; ++e) {
        accph[e] += __shfl_xor(accph[e], 16, 64);
        accph[e] += __shfl_xor(accph[e], 32, 64);
        accpt[e] += __shfl_xor(accpt[e], 16, 64);
        accpt[e] += __shfl_xor(accpt[e], 32, 64);
    }
    if ((threadIdx.x & 63) < 16) {
        const int o = TEN3(b, i, k8);
        #pragma unroll
        for (int e = 0; e < 8; ++e) {
            atomicAdd(&acc_h[o + e], accph[e]);
            atomicAdd(&acc_t[o + e], accpt[e]);
        }
    }
}

// ---------------- fallback path (R0 f32 kernels, unchanged) ----------------
__global__ __launch_bounds__(128) void k1_kernel(
    const float* __restrict__ r_psh, const float* __restrict__ r_pst,
    const float* __restrict__ f_pst,
    const float* __restrict__ m_r, const float* __restrict__ m_f,
    const float* __restrict__ sig_s, const float* __restrict__ sig_h, const float* __restrict__ sig_t,
    float* __restrict__ acc_s, float* __restrict__ acc_h, float* __restrict__ acc_t)
{
    const int j = blockIdx.y, b = blockIdx.z;
    const int i0 = blockIdx.x * 32;
    const int sub = threadIdx.x >> 5;
    const int kq  = threadIdx.x & 31;
    const int k4  = kq << 2;

    const float4 ss_jk = ld4(&sig_s[TEN3(b, j, k4)]);
    const float4 st_jk = ld4(&sig_t[TEN3(b, j, k4)]);

    float4 accspan = make_float4(0.f, 0.f, 0.f, 0.f);
    float4 accpt   = make_float4(0.f, 0.f, 0.f, 0.f);

    const long long base_bj = (long long)b * TT * TT * TT + (long long)j * TT + k4;

    #pragma unroll 2
    for (int step = 0; step < 8; ++step) {
        const int i = i0 + step * 4 + sub;
        const long long rb = base_bj + (long long)i * (TT * TT);

        const float4 vm  = ld4(&m_r[rb]);
        const float4 v1  = mul4(ld4(&r_psh[rb]), vm);
        const float4 v2  = mul4(ld4(&r_pst[rb]), vm);
        const float4 vmf = ld4(&m_f[rb]);
        const float4 v4  = mul4(ld4(&f_pst[rb]), vmf);

        const float  sh_ij = sig_h[TEN3(b, i, j)];
        const float  ss_ij = sig_s[TEN3(b, i, j)];
        const float4 st_ik = ld4(&sig_t[TEN3(b, i, k4)]);

        accspan = fma4s(sh_ij, v1, accspan);
        accspan = fma4v(st_ik, v2, accspan);
        accpt   = fma4s(ss_ij, v4, accpt);

        float red5 = dot4(ss_jk, v1);
        float red4 = dot4(st_jk, v4);
        #pragma unroll
        for (int off = 16; off; off >>= 1) {
            red5 += __shfl_xor(red5, off, 64);
            red4 += __shfl_xor(red4, off, 64);
        }
        if (kq == 0) {
            atomicAdd(&acc_h[TEN3(b, i, j)], red5);
            atomicAdd(&acc_s[TEN3(b, i, j)], red4);
        }
    }

    accspan.x += __shfl_xor(accspan.x, 32, 64);
    accspan.y += __shfl_xor(accspan.y, 32, 64);
    accspan.z += __shfl_xor(accspan.z, 32, 64);
    accspan.w += __shfl_xor(accspan.w, 32, 64);
    accpt.x += __shfl_xor(accpt.x, 32, 64);
    accpt.y += __shfl_xor(accpt.y, 32, 64);
    accpt.z += __shfl_xor(accpt.z, 32, 64);
    accpt.w += __shfl_xor(accpt.w, 32, 64);
    if (sub == 0 || sub == 2) {
        const int o = TEN3(b, j, k4);
        atomicAdd(&acc_s[o + 0], accspan.x);
        atomicAdd(&acc_s[o + 1], accspan.y);
        atomicAdd(&acc_s[o + 2], accspan.z);
        atomicAdd(&acc_s[o + 3], accspan.w);
        atomicAdd(&acc_t[o + 0], accpt.x);
        atomicAdd(&acc_t[o + 1], accpt.y);
        atomicAdd(&acc_t[o + 2], accpt.z);
        atomicAdd(&acc_t[o + 3], accpt.w);
    }
}

__global__ __launch_bounds__(128) void k2_kernel(
    const float* __restrict__ f_psh, const float* __restrict__ s_h, const float* __restrict__ s_t,
    const float* __restrict__ c_h, const float* __restrict__ c_t, const float* __restrict__ r_pst,
    const float* __restrict__ m_sp, const float* __restrict__ m_sb,
    const float* __restrict__ m_cp, const float* __restrict__ m_r,
    const float* __restrict__ sig_s, const float* __restrict__ sig_h, const float* __restrict__ sig_t,
    float* __restrict__ acc_s, float* __restrict__ acc_h, float* __restrict__ acc_t)
{
    const int i = blockIdx.y, b = blockIdx.z;
    const int j0 = blockIdx.x * 32;
    const int sub = threadIdx.x >> 5;
    const int kq  = threadIdx.x & 31;
    const int k4  = kq << 2;

    const float4 sh_ik = ld4(&sig_h[TEN3(b, i, k4)]);
    const float4 st_ik = ld4(&sig_t[TEN3(b, i, k4)]);

    float4 accph = make_float4(0.f, 0.f, 0.f, 0.f);
    float4 accpt = make_float4(0.f, 0.f, 0.f, 0.f);

    const long long base_bi = (long long)b * TT * TT * TT + (long long)i * (TT * TT) + k4;

    #pragma unroll 2
    for (int step = 0; step < 8; ++step) {
        const int j = j0 + step * 4 + sub;
        const long long rb = base_bi + (long long)j * TT;

        const float4 msp = ld4(&m_sp[rb]);
        const float4 v3  = mul4(ld4(&f_psh[rb]), msp);
        const float4 msb = ld4(&m_sb[rb]);
        const float4 v6  = mul4(ld4(&s_h[rb]), msb);
        const float4 v9  = mul4(ld4(&s_t[rb]), msb);
        const float4 mcp = ld4(&m_cp[rb]);
        const float4 v7  = mul4(ld4(&c_h[rb]), mcp);
        const float4 v11 = mul4(ld4(&c_t[rb]), mcp);
        const float4 mr  = ld4(&m_r[rb]);
        const float4 v10 = mul4(ld4(&r_pst[rb]), mr);

        const float  ss_ij = sig_s[TEN3(b, i, j)];
        const float4 sh_jk = ld4(&sig_h[TEN3(b, j, k4)]);
        const float4 st_jk = ld4(&sig_t[TEN3(b, j, k4)]);
        const float4 ss_jk = ld4(&sig_s[TEN3(b, j, k4)]);

        accph = fma4s(ss_ij, v3,  accph);
        accph = fma4v(sh_jk, v7,  accph);
        accpt = fma4v(st_jk, v11, accpt);
        accpt = fma4v(ss_jk, v10, accpt);

        float red3 = dot4(sh_ik, v3);
        float red6 = dot4(sh_ik, v6);
        float red9 = dot4(st_ik, v9);
        #pragma unroll
        for (int off = 16; off; off >>= 1) {
            red3 += __shfl_xor(red3, off, 64);
            red6 += __shfl_xor(red6, off, 64);
            red9 += __shfl_xor(red9, off, 64);
        }
        if (kq == 0) {
            atomicAdd(&acc_s[TEN3(b, i, j)], red3);
            atomicAdd(&acc_h[TEN3(b, i, j)], red6);
            atomicAdd(&acc_t[TEN3(b, i, j)], red9);
        }
    }

    accph.x += __shfl_xor(accph.x, 32, 64);
    accph.y += __shfl_xor(accph.y, 32, 64);
    accph.z += __shfl_xor(accph.z, 32, 64);
    accph.w += __shfl_xor(accph.w, 32, 64);
    accpt.x += __shfl_xor(accpt.x, 32, 64);
    accpt.y += __shfl_xor(accpt.y, 32, 64);
    accpt.z += __shfl_xor(accpt.z, 32, 64);
    accpt.w += __shfl_xor(accpt.w, 32, 64);
    if (sub == 0 || sub == 2) {
        const int o = TEN3(b, i, k4);
        atomicAdd(&acc_h[o + 0], accph.x);
        atomicAdd(&acc_h[o + 1], accph.y);
        atomicAdd(&acc_h[o + 2], accph.z);
        atomicAdd(&acc_h[o + 3], accph.w);
        atomicAdd(&acc_t[o + 0], accpt.x);
        atomicAdd(&acc_t[o + 1], accpt.y);
        atomicAdd(&acc_t[o + 2], accpt.z);
        atomicAdd(&acc_t[o + 3], accpt.w);
    }
}

extern "C" void kernel_launch(void* const* d_in, const int* in_sizes, int n_in,
                              void* d_out, int out_size, void* d_ws, size_t ws_size,
                              hipStream_t stream)
{
    const float* span      = (const float*)d_in[0];
    const float* ph        = (const float*)d_in[1];
    const float* pt        = (const float*)d_in[2];
    const float* rspan_psh = (const float*)d_in[3];
    const float* rspan_pst = (const float*)d_in[4];
    const float* fspan_psh = (const float*)d_in[5];
    const float* fspan_pst = (const float*)d_in[6];
    const float* ph_sib    = (const float*)d_in[7];
    const float* pt_sib    = (const float*)d_in[8];
    const float* ph_cop    = (const float*)d_in[9];
    const float* pt_cop    = (const float*)d_in[10];
    const float* m_p2rspan = (const float*)d_in[11];
    const float* m_psib    = (const float*)d_in[12];
    const float* m_pcop    = (const float*)d_in[13];
    const float* m_pspan2r = (const float*)d_in[14];

    float* ws = (float*)d_ws;
    float* sig_s = ws + 0 * NT;
    float* sig_h = ws + 1 * NT;
    float* sig_t = ws + 2 * NT;
    float* A_s   = ws + 3 * NT;
    float* A_h   = ws + 4 * NT;
    float* A_t   = ws + 5 * NT;
    float* B_s   = ws + 6 * NT;
    float* B_h   = ws + 7 * NT;
    float* B_t   = ws + 8 * NT;
    float* O_s   = (float*)d_out;
    float* O_h   = O_s + NT;
    float* O_t   = O_s + 2 * NT;

    struct Iter { const float *qs, *qh, *qt; float *as, *ah, *at; };
    const Iter it[3] = {
        { span, ph, pt,  A_s, A_h, A_t },
        { A_s, A_h, A_t, B_s, B_h, B_t },
        { B_s, B_h, B_t, O_s, O_h, O_t },
    };

    const size_t fp16_bytes_needed = (size_t)9 * NT * 4 + 8ull * N4 * 2;
    const bool fast = (ws_size >= fp16_bytes_needed);

    if (fast) {
        _Float16* hbase = (_Float16*)(ws + 9 * NT);
        _Float16* t_r1  = hbase + 0 * N4;
        _Float16* t_r2  = hbase + 1 * N4;
        _Float16* t_f3  = hbase + 2 * N4;
        _Float16* t_f4  = hbase + 3 * N4;
        _Float16* t_s6  = hbase + 4 * N4;
        _Float16* t_s9  = hbase + 5 * N4;
        _Float16* t_c7  = hbase + 6 * N4;
        _Float16* t_c11 = hbase + 7 * N4;

        pm_kernel<<<(int)(N4 / 8 / 256), 256, 0, stream>>>(
            rspan_psh, rspan_pst, m_p2rspan,
            fspan_psh, fspan_pst, m_pspan2r,
            ph_sib, pt_sib, m_psib,
            ph_cop, pt_cop, m_pcop,
            t_r1, t_r2, t_f3, t_f4, t_s6, t_s9, t_c7, t_c11);

        const dim3 grid8(8, TT, BB);
        const dim3 blk(128);
        for (int t = 0; t < 3; ++t) {
            prep_kernel<<<NT / 256, 256, 0, stream>>>(
                it[t].qs, it[t].qh, it[t].qt, span, ph, pt,
                sig_s, sig_h, sig_t, it[t].as, it[t].ah, it[t].at);
            k1h_kernel<<<grid8, blk, 0, stream>>>(
                t_r1, t_r2, t_f4,
                sig_s, sig_h, sig_t, it[t].as, it[t].ah, it[t].at);
            k2h_kernel<<<grid8, blk, 0, stream>>>(
                t_f3, t_s6, t_s9, t_c7, t_c11, t_r2,
                sig_s, sig_h, sig_t, it[t].as, it[t].ah, it[t].at);
        }
    } else {
        const dim3 grid4(4, TT, BB);
        const dim3 blk(128);
        for (int t = 0; t < 3; ++t) {
            prep_kernel<<<NT / 256, 256, 0, stream>>>(
                it[t].qs, it[t].qh, it[t].qt, span, ph, pt,
                sig_s, sig_h, sig_t, it[t].as, it[t].ah, it[t].at);
            k1_kernel<<<grid4, blk, 0, stream>>>(
                rspan_psh, rspan_pst, fspan_pst, m_p2rspan, m_pspan2r,
                sig_s, sig_h, sig_t, it[t].as, it[t].ah, it[t].at);
            k2_kernel<<<grid4, blk, 0, stream>>>(
                fspan_psh, ph_sib, pt_sib, ph_cop, pt_cop, rspan_pst,
                m_pspan2r, m_psib, m_pcop, m_p2rspan,
                sig_s, sig_h, sig_t, it[t].as, it[t].ah, it[t].at);
        }
    }
}

// Round 4
// 215.983 us; speedup vs baseline: 2.3813x; 2.3813x over previous
//
#include <hip/hip_runtime.h>
#include <math.h>

#define TT 128
#define BB 4
#define NT (BB*TT*TT)                 // 65536 elements per [B,T,T]
#define N4 ((size_t)BB*TT*TT*TT)      // 8388608 elements per [B,T,T,T]
#define TEN3(b,x,y) (((b)*TT + (x))*TT + (y))

typedef _Float16 h4v __attribute__((ext_vector_type(4)));
typedef _Float16 h8v __attribute__((ext_vector_type(8)));

__device__ __forceinline__ float sigm(float x) { return 1.0f / (1.0f + __expf(-x)); }
__device__ __forceinline__ float4 ld4(const float* __restrict__ p) {
    return *reinterpret_cast<const float4*>(p);
}
__device__ __forceinline__ float4 fma4s(const float s, const float4 v, const float4 acc) {
    return make_float4(fmaf(s, v.x, acc.x), fmaf(s, v.y, acc.y),
                       fmaf(s, v.z, acc.z), fmaf(s, v.w, acc.w));
}
__device__ __forceinline__ float4 fma4v(const float4 s, const float4 v, const float4 acc) {
    return make_float4(fmaf(s.x, v.x, acc.x), fmaf(s.y, v.y, acc.y),
                       fmaf(s.z, v.z, acc.z), fmaf(s.w, v.w, acc.w));
}
__device__ __forceinline__ float dot4(const float4 a, const float4 b) {
    return a.x*b.x + a.y*b.y + a.z*b.z + a.w*b.w;
}
__device__ __forceinline__ float4 cvt4(const h4v h) {
    return make_float4((float)h[0], (float)h[1], (float)h[2], (float)h[3]);
}
__device__ __forceinline__ h4v ldh4(const _Float16* __restrict__ p) {
    return *reinterpret_cast<const h4v*>(p);
}

// ---------------- one-shot: masked fp16 precompute (R1-proven pattern) ----------------
__device__ __forceinline__ void mask_cvt_store(
    const float* __restrict__ v, size_t idx,
    const float4 m0, const float4 m1, _Float16* __restrict__ o)
{
    const float4 a = ld4(v + idx);
    const float4 b = ld4(v + idx + 4);
    h8v h;
    h[0]=(_Float16)(a.x*m0.x); h[1]=(_Float16)(a.y*m0.y);
    h[2]=(_Float16)(a.z*m0.z); h[3]=(_Float16)(a.w*m0.w);
    h[4]=(_Float16)(b.x*m1.x); h[5]=(_Float16)(b.y*m1.y);
    h[6]=(_Float16)(b.z*m1.z); h[7]=(_Float16)(b.w*m1.w);
    *reinterpret_cast<h8v*>(o + idx) = h;
}

__global__ __launch_bounds__(256) void pm_kernel(
    const float* __restrict__ rspan_psh, const float* __restrict__ rspan_pst, const float* __restrict__ m_r,
    const float* __restrict__ fspan_psh, const float* __restrict__ fspan_pst, const float* __restrict__ m_f,
    const float* __restrict__ ph_sib,    const float* __restrict__ pt_sib,    const float* __restrict__ m_sb,
    const float* __restrict__ ph_cop,    const float* __restrict__ pt_cop,    const float* __restrict__ m_cp,
    _Float16* __restrict__ t_r1, _Float16* __restrict__ t_r2,
    _Float16* __restrict__ t_f3, _Float16* __restrict__ t_f4,
    _Float16* __restrict__ t_s6, _Float16* __restrict__ t_s9,
    _Float16* __restrict__ t_c7, _Float16* __restrict__ t_c11)
{
    const size_t idx = ((size_t)blockIdx.x * 256 + threadIdx.x) * 8;
    {
        const float4 m0 = ld4(m_r + idx), m1 = ld4(m_r + idx + 4);
        mask_cvt_store(rspan_psh, idx, m0, m1, t_r1);
        mask_cvt_store(rspan_pst, idx, m0, m1, t_r2);
    }
    {
        const float4 m0 = ld4(m_f + idx), m1 = ld4(m_f + idx + 4);
        mask_cvt_store(fspan_psh, idx, m0, m1, t_f3);
        mask_cvt_store(fspan_pst, idx, m0, m1, t_f4);
    }
    {
        const float4 m0 = ld4(m_sb + idx), m1 = ld4(m_sb + idx + 4);
        mask_cvt_store(ph_sib, idx, m0, m1, t_s6);
        mask_cvt_store(pt_sib, idx, m0, m1, t_s9);
    }
    {
        const float4 m0 = ld4(m_cp + idx), m1 = ld4(m_cp + idx + 4);
        mask_cvt_store(ph_cop, idx, m0, m1, t_c7);
        mask_cvt_store(pt_cop, idx, m0, m1, t_c11);
    }
}

// ---------------- per-iteration prep ----------------
__global__ __launch_bounds__(256) void prep_kernel(
    const float* __restrict__ q_s, const float* __restrict__ q_h, const float* __restrict__ q_t,
    const float* __restrict__ span, const float* __restrict__ ph, const float* __restrict__ pt,
    float* __restrict__ sig_s, float* __restrict__ sig_h, float* __restrict__ sig_t,
    float* __restrict__ acc_s, float* __restrict__ acc_h, float* __restrict__ acc_t)
{
    const int idx = blockIdx.x * 256 + threadIdx.x;
    sig_s[idx] = sigm(q_s[idx]);
    sig_h[idx] = sigm(q_h[idx]);
    sig_t[idx] = sigm(q_t[idx]);
    acc_s[idx] = span[idx];
    acc_h[idx] = ph[idx];
    acc_t[idx] = pt[idx];
}

// K1: block fixed (b,j); 16 i-rows per block (2 steps x 8 sub-rows); 256 threads.
// (1) span[j,k] += sh[i,j]*v1   (2) span[j,k] += st[i,k]*v2
// (5) ph[i,j]  += sum_k ss[j,k]*v1
// (4) span[i,j] += sum_k st[j,k]*v4   (12) pt[j,k] += ss[i,j]*v4
__global__ __launch_bounds__(256) void k1f_kernel(
    const _Float16* __restrict__ t_r1, const _Float16* __restrict__ t_r2,
    const _Float16* __restrict__ t_f4,
    const float* __restrict__ sig_s, const float* __restrict__ sig_h, const float* __restrict__ sig_t,
    float* __restrict__ acc_s, float* __restrict__ acc_h, float* __restrict__ acc_t)
{
    const int j = blockIdx.y, b = blockIdx.z;
    const int i0 = blockIdx.x * 16;
    const int sub = threadIdx.x >> 5;   // 0..7
    const int kq  = threadIdx.x & 31;
    const int k4  = kq << 2;

    const float4 ss_jk = ld4(&sig_s[TEN3(b, j, k4)]);
    const float4 st_jk = ld4(&sig_t[TEN3(b, j, k4)]);

    float4 accspan = make_float4(0.f,0.f,0.f,0.f);
    float4 accpt   = make_float4(0.f,0.f,0.f,0.f);
    float red5[2], red4[2];

    const size_t base = (size_t)b * TT * TT * TT + (size_t)j * TT + k4;

    #pragma unroll
    for (int step = 0; step < 2; ++step) {
        const int i = i0 + step * 8 + sub;
        const size_t rb = base + (size_t)i * (TT * TT);

        const float4 v1 = cvt4(ldh4(t_r1 + rb));
        const float4 v2 = cvt4(ldh4(t_r2 + rb));
        const float4 v4 = cvt4(ldh4(t_f4 + rb));

        const float  sh_ij = sig_h[TEN3(b, i, j)];
        const float  ss_ij = sig_s[TEN3(b, i, j)];
        const float4 st_ik = ld4(&sig_t[TEN3(b, i, k4)]);

        accspan = fma4s(sh_ij, v1, accspan);   // (1)
        accspan = fma4v(st_ik, v2, accspan);   // (2)
        accpt   = fma4s(ss_ij, v4, accpt);     // (12)
        red5[step] = dot4(ss_jk, v1);          // (5)
        red4[step] = dot4(st_jk, v4);          // (4)
    }

    // deferred cross-lane reduction: 4 independent chains
    #pragma unroll
    for (int off = 16; off; off >>= 1) {
        #pragma unroll
        for (int s2 = 0; s2 < 2; ++s2) {
            red5[s2] += __shfl_xor(red5[s2], off, 64);
            red4[s2] += __shfl_xor(red4[s2], off, 64);
        }
    }
    if (kq == 0) {
        #pragma unroll
        for (int s2 = 0; s2 < 2; ++s2) {
            const int i = i0 + s2 * 8 + sub;
            atomicAdd(&acc_h[TEN3(b, i, j)], red5[s2]);
            atomicAdd(&acc_s[TEN3(b, i, j)], red4[s2]);
        }
    }

    // block-end LDS reduce over the 8 sub-rows for the k-indexed accumulators
    __shared__ float s_red[2][8][128];
    *reinterpret_cast<float4*>(&s_red[0][sub][k4]) = accspan;
    *reinterpret_cast<float4*>(&s_red[1][sub][k4]) = accpt;
    __syncthreads();
    const int which = threadIdx.x >> 7;   // 0: span, 1: pt
    const int e     = threadIdx.x & 127;
    float s = 0.f;
    #pragma unroll
    for (int u = 0; u < 8; ++u) s += s_red[which][u][e];
    float* dst = which ? acc_t : acc_s;
    atomicAdd(&dst[TEN3(b, j, e)], s);
}

// K2: block fixed (b,i); 16 j-rows per block (2 steps x 8 sub-rows); 256 threads.
// (3) span[i,j] += sum_k sh[i,k]*v3    (8)  ph[i,k] += ss[i,j]*v3
// (6) ph[i,j]  += sum_k sh[i,k]*v6     (9)  pt[i,j] += sum_k st[i,k]*v9
// (7) ph[i,k]  += sh[j,k]*v7           (11) pt[i,k] += st[j,k]*v11
// (10) pt[i,k] += ss[j,k]*v10
__global__ __launch_bounds__(256) void k2f_kernel(
    const _Float16* __restrict__ t_f3, const _Float16* __restrict__ t_s6,
    const _Float16* __restrict__ t_s9, const _Float16* __restrict__ t_c7,
    const _Float16* __restrict__ t_c11, const _Float16* __restrict__ t_r2,
    const float* __restrict__ sig_s, const float* __restrict__ sig_h, const float* __restrict__ sig_t,
    float* __restrict__ acc_s, float* __restrict__ acc_h, float* __restrict__ acc_t)
{
    const int i = blockIdx.y, b = blockIdx.z;
    const int j0 = blockIdx.x * 16;
    const int sub = threadIdx.x >> 5;
    const int kq  = threadIdx.x & 31;
    const int k4  = kq << 2;

    const float4 sh_ik = ld4(&sig_h[TEN3(b, i, k4)]);
    const float4 st_ik = ld4(&sig_t[TEN3(b, i, k4)]);

    float4 accph = make_float4(0.f,0.f,0.f,0.f);
    float4 accpt = make_float4(0.f,0.f,0.f,0.f);
    float red3[2], red6[2], red9[2];

    const size_t base = (size_t)b * TT * TT * TT + (size_t)i * (TT * TT) + k4;

    #pragma unroll
    for (int step = 0; step < 2; ++step) {
        const int j = j0 + step * 8 + sub;
        const size_t rb = base + (size_t)j * TT;

        const float4 v3  = cvt4(ldh4(t_f3  + rb));
        const float4 v6  = cvt4(ldh4(t_s6  + rb));
        const float4 v9  = cvt4(ldh4(t_s9  + rb));
        const float4 v7  = cvt4(ldh4(t_c7  + rb));
        const float4 v11 = cvt4(ldh4(t_c11 + rb));
        const float4 v10 = cvt4(ldh4(t_r2  + rb));

        const float  ss_ij = sig_s[TEN3(b, i, j)];
        const float4 sh_jk = ld4(&sig_h[TEN3(b, j, k4)]);
        const float4 st_jk = ld4(&sig_t[TEN3(b, j, k4)]);
        const float4 ss_jk = ld4(&sig_s[TEN3(b, j, k4)]);

        accph = fma4s(ss_ij, v3,  accph);   // (8)
        accph = fma4v(sh_jk, v7,  accph);   // (7)
        accpt = fma4v(st_jk, v11, accpt);   // (11)
        accpt = fma4v(ss_jk, v10, accpt);   // (10)

        red3[step] = dot4(sh_ik, v3);       // (3)
        red6[step] = dot4(sh_ik, v6);       // (6)
        red9[step] = dot4(st_ik, v9);       // (9)
    }

    #pragma unroll
    for (int off = 16; off; off >>= 1) {
        #pragma unroll
        for (int s2 = 0; s2 < 2; ++s2) {
            red3[s2] += __shfl_xor(red3[s2], off, 64);
            red6[s2] += __shfl_xor(red6[s2], off, 64);
            red9[s2] += __shfl_xor(red9[s2], off, 64);
        }
    }
    if (kq == 0) {
        #pragma unroll
        for (int s2 = 0; s2 < 2; ++s2) {
            const int j = j0 + s2 * 8 + sub;
            atomicAdd(&acc_s[TEN3(b, i, j)], red3[s2]);
            atomicAdd(&acc_h[TEN3(b, i, j)], red6[s2]);
            atomicAdd(&acc_t[TEN3(b, i, j)], red9[s2]);
        }
    }

    __shared__ float s_red[2][8][128];
    *reinterpret_cast<float4*>(&s_red[0][sub][k4]) = accph;
    *reinterpret_cast<float4*>(&s_red[1][sub][k4]) = accpt;
    __syncthreads();
    const int which = threadIdx.x >> 7;   // 0: ph, 1: pt
    const int e     = threadIdx.x & 127;
    float s = 0.f;
    #pragma unroll
    for (int u = 0; u < 8; ++u) s += s_red[which][u][e];
    float* dst = which ? acc_t : acc_h;
    atomicAdd(&dst[TEN3(b, i, e)], s);
}

extern "C" void kernel_launch(void* const* d_in, const int* in_sizes, int n_in,
                              void* d_out, int out_size, void* d_ws, size_t ws_size,
                              hipStream_t stream)
{
    const float* span      = (const float*)d_in[0];
    const float* ph        = (const float*)d_in[1];
    const float* pt        = (const float*)d_in[2];
    const float* rspan_psh = (const float*)d_in[3];
    const float* rspan_pst = (const float*)d_in[4];
    const float* fspan_psh = (const float*)d_in[5];
    const float* fspan_pst = (const float*)d_in[6];
    const float* ph_sib    = (const float*)d_in[7];
    const float* pt_sib    = (const float*)d_in[8];
    const float* ph_cop    = (const float*)d_in[9];
    const float* pt_cop    = (const float*)d_in[10];
    const float* m_p2rspan = (const float*)d_in[11];
    const float* m_psib    = (const float*)d_in[12];
    const float* m_pcop    = (const float*)d_in[13];
    const float* m_pspan2r = (const float*)d_in[14];

    float* ws = (float*)d_ws;
    float* sig_s = ws + 0 * NT;
    float* sig_h = ws + 1 * NT;
    float* sig_t = ws + 2 * NT;
    float* A_s   = ws + 3 * NT;
    float* A_h   = ws + 4 * NT;
    float* A_t   = ws + 5 * NT;
    float* B_s   = ws + 6 * NT;
    float* B_h   = ws + 7 * NT;
    float* B_t   = ws + 8 * NT;
    float* O_s   = (float*)d_out;
    float* O_h   = O_s + NT;
    float* O_t   = O_s + 2 * NT;

    _Float16* hbase = (_Float16*)(ws + 9 * NT);
    _Float16* t_r1  = hbase + 0 * N4;
    _Float16* t_r2  = hbase + 1 * N4;
    _Float16* t_f4  = hbase + 2 * N4;
    _Float16* t_f3  = hbase + 3 * N4;
    _Float16* t_s6  = hbase + 4 * N4;
    _Float16* t_s9  = hbase + 5 * N4;
    _Float16* t_c7  = hbase + 6 * N4;
    _Float16* t_c11 = hbase + 7 * N4;

    struct Iter { const float *qs, *qh, *qt; float *as, *ah, *at; };
    const Iter it[3] = {
        { span, ph, pt,  A_s, A_h, A_t },
        { A_s, A_h, A_t, B_s, B_h, B_t },
        { B_s, B_h, B_t, O_s, O_h, O_t },
    };

    // One-shot masked fp16 precompute (R1-proven replay-safe pattern).
    pm_kernel<<<(int)(N4 / 8 / 256), 256, 0, stream>>>(
        rspan_psh, rspan_pst, m_p2rspan,
        fspan_psh, fspan_pst, m_pspan2r,
        ph_sib, pt_sib, m_psib,
        ph_cop, pt_cop, m_pcop,
        t_r1, t_r2, t_f3, t_f4, t_s6, t_s9, t_c7, t_c11);

    const dim3 grid8(8, TT, BB);   // 4096 blocks x 256 thr
    const dim3 blk(256);

    for (int t = 0; t < 3; ++t) {
        prep_kernel<<<NT / 256, 256, 0, stream>>>(
            it[t].qs, it[t].qh, it[t].qt, span, ph, pt,
            sig_s, sig_h, sig_t, it[t].as, it[t].ah, it[t].at);
        k1f_kernel<<<grid8, blk, 0, stream>>>(
            t_r1, t_r2, t_f4,
            sig_s, sig_h, sig_t, it[t].as, it[t].ah, it[t].at);
        k2f_kernel<<<grid8, blk, 0, stream>>>(
            t_f3, t_s6, t_s9, t_c7, t_c11, t_r2,
            sig_s, sig_h, sig_t, it[t].as, it[t].ah, it[t].at);
    }
}